// Round 1
// baseline (75.797 us; speedup 1.0000x reference)
//
#include <hip/hip_runtime.h>
#include <math.h>

// Problem constants (fixed by setup_inputs): bs=16, Q=300, C=2, P=320
#define BS 16
#define QN 300
#define CN 2
#define PN 320
#define NN (BS * QN)   // 4800 query rows
#define KPRED 53
#define KTGT 54
#define TILE_N 4       // query rows per block -> 1200 blocks

// ---------------------------------------------------------------------------
// Preprocess: transpose + de-interleave tgt_kpts [320][54] -> tgtT [54][320].
//   rows  0..17 : x coords   tgt[p*54 + 3j]
//   rows 18..35 : y coords   tgt[p*54 + 3j+1]
//   rows 36..53 : vis/class  tgt[p*54 + 3j+2]
// Main kernel then reads lane p <- tgtT[row*320 + p]: perfectly coalesced.
// One-time 69 KB shuffle; reads are uncoalesced but trivial in volume.
// ---------------------------------------------------------------------------
__global__ __launch_bounds__(PN) void transpose_tgt_kernel(
    const float* __restrict__ tgt_kpts,   // [P, 54]
    float* __restrict__ tgtT)             // [54, P]
{
    const int j = blockIdx.x;             // 0..53 (uniform per block)
    const int p = threadIdx.x;            // 0..319
    const int grp = j / 18;               // 0=x, 1=y, 2=w
    const int idx = j - 18 * grp;         // joint index
    const int c = 3 * idx + grp;          // source column in [0,54)
    tgtT[j * PN + p] = tgt_kpts[p * KTGT + c];
}

// thread = target p (0..319, 5 waves/block); block handles TILE_N query rows.
// Target features live in registers for the whole block, loaded COALESCED
// from the transposed table. tgt[:,5::3] (kpts-class vec) aliases the vis
// slots [:,2::3] shifted by one joint, so one w[] array serves both.
__global__ __launch_bounds__(PN) void hungarian_cost_kernel(
    const float* __restrict__ pred_logits,  // [N, 2]
    const float* __restrict__ pred_kpts,    // [N, 53]
    const float* __restrict__ tgtT,         // [54, P] transposed targets
    const int*   __restrict__ tgt_ids,      // [P]
    float* __restrict__ out)                // [N, P]
{
    const int p  = threadIdx.x;
    const int n0 = blockIdx.x * TILE_N;

    // ---- per-thread target features (coalesced: lane p at column p) ----
    float tx[18], ty[18], w[18];
    #pragma unroll
    for (int j = 0; j < 18; ++j) tx[j] = tgtT[j * PN + p];
    #pragma unroll
    for (int j = 0; j < 18; ++j) ty[j] = tgtT[(18 + j) * PN + p];
    unsigned vmask = 0u;
    #pragma unroll
    for (int j = 0; j < 18; ++j) {
        w[j] = tgtT[(36 + j) * PN + p];
        vmask |= (w[j] == 1.0f) ? (1u << j) : 0u;
    }
    const int cls = tgt_ids[p];

    // logits for all TILE_N rows, one batched (uniform -> SGPR) load
    float lg[2 * TILE_N];
    #pragma unroll
    for (int i = 0; i < 2 * TILE_N; ++i) lg[i] = pred_logits[n0 * CN + i];

    #pragma unroll
    for (int ni = 0; ni < TILE_N; ++ni) {
        const int n = n0 + ni;

        float k[KPRED];   // wave-uniform -> compiler keeps in SGPRs
        {
            const float* kp = pred_kpts + (size_t)n * KPRED;
            #pragma unroll
            for (int i = 0; i < KPRED; ++i) k[i] = kp[i];
        }

        const float dx0 = k[0] - tx[0];
        const float dy0 = k[1] - ty[0];

        float cd = 0.0f;   // cost_deltas
        float ck = 0.0f;   // cost_kpts: xa - txa = 2*dx + dx0
        float cq = 0.0f;   // kpts-class squared distance
        #pragma unroll
        for (int j = 1; j < 18; ++j) {
            const float vj = (float)((vmask >> j) & 1u);
            const float dx = k[3 * j - 1] - tx[j];
            const float dy = k[3 * j]     - ty[j];
            cd = fmaf(vj, fabsf(dx) + fabsf(dy), cd);
            const float ax = fmaf(2.0f, dx, dx0);
            const float ay = fmaf(2.0f, dy, dy0);
            ck = fmaf(vj, fabsf(ax) + fabsf(ay), ck);
            const float d = k[3 * j + 1] - w[j];   // tid[j-1] == w[j]
            cq = fmaf(d, d, cq);
        }

        // cost_ctrs = vis0 * ||(dx0, dy0)||
        const float v0 = (float)(vmask & 1u);
        const float cc = v0 * sqrtf(fmaf(dx0, dx0, dy0 * dy0));

        // cost_class = -softmax(logits)[cls]
        const float l0 = lg[2 * ni], l1 = lg[2 * ni + 1];
        const float m  = fmaxf(l0, l1);
        const float e0 = __expf(l0 - m);
        const float e1 = __expf(l1 - m);
        const float inv = 1.0f / (e0 + e1);
        const float ccls = -((cls == 0) ? e0 : e1) * inv;

        out[(size_t)n * PN + p] = ck + cc + cd + ccls + sqrtf(cq);
    }
}

extern "C" void kernel_launch(void* const* d_in, const int* in_sizes, int n_in,
                              void* d_out, int out_size, void* d_ws, size_t ws_size,
                              hipStream_t stream) {
    const float* pred_logits = (const float*)d_in[0];
    const float* pred_kpts   = (const float*)d_in[1];
    const float* tgt_kpts    = (const float*)d_in[2];
    const int*   tgt_ids     = (const int*)d_in[3];
    float* out  = (float*)d_out;
    float* tgtT = (float*)d_ws;   // 54*320*4 = 69120 B scratch

    // 1) one-time transpose of the target table (stream-ordered before main)
    hipLaunchKernelGGL(transpose_tgt_kernel, dim3(KTGT), dim3(PN), 0, stream,
                       tgt_kpts, tgtT);

    // 2) main cost kernel
    hipLaunchKernelGGL(hungarian_cost_kernel, dim3(NN / TILE_N), dim3(PN), 0, stream,
                       pred_logits, pred_kpts, tgtT, tgt_ids, out);
}

// Round 4
// 73.957 us; speedup vs baseline: 1.0249x; 1.0249x over previous
//
#include <hip/hip_runtime.h>
#include <math.h>

// Problem constants (fixed by setup_inputs): bs=16, Q=300, C=2, P=320
#define BS 16
#define QN 300
#define CN 2
#define PN 320
#define NN (BS * QN)   // 4800 query rows
#define KPRED 53
#define KTGT 54
#define TILE_N 4       // query rows per block -> 1200 blocks

// thread = target p (0..319, 5 waves/block); block handles TILE_N query rows.
// Target features in registers for the whole block. Key register trick:
// tgt_kpts[:,5::3] (kpts-class vec) aliases the vis slots [:,2::3] shifted by
// one joint, so one raw w[] array serves both; vis itself is a bitmask.
// NOTE: proven-passing baseline structure (rounds 0/1). Rounds 1-3 A/B showed
// dur_us is insensitive to the target-gather pattern, dispatch count, and
// memory plan -> harness-floor bound. Keep constructs strictly conservative.
__global__ __launch_bounds__(PN) void hungarian_cost_kernel(
    const float* __restrict__ pred_logits,  // [N, 2]
    const float* __restrict__ pred_kpts,    // [N, 53]
    const float* __restrict__ tgt_kpts,     // [P, 54]
    const int*   __restrict__ tgt_ids,      // [P]
    float* __restrict__ out)                // [N, P]
{
    const int p  = threadIdx.x;
    const int n0 = blockIdx.x * TILE_N;

    // ---- per-thread target features ----
    float tx[18], ty[18], w[18];   // w[j] = t[3j+2] raw (vis slot / class tgt)
    unsigned vmask = 0u;
    {
        const float* t = tgt_kpts + (size_t)p * KTGT;
        #pragma unroll
        for (int j = 0; j < 18; ++j) {
            tx[j] = t[3 * j];
            ty[j] = t[3 * j + 1];
            const float vv = t[3 * j + 2];
            w[j] = vv;
            vmask |= (vv == 1.0f) ? (1u << j) : 0u;
        }
    }
    const int cls = tgt_ids[p];

    // logits for all TILE_N rows, one batched (uniform -> scalar) load
    float lg[2 * TILE_N];
    #pragma unroll
    for (int i = 0; i < 2 * TILE_N; ++i) lg[i] = pred_logits[n0 * CN + i];

    #pragma unroll
    for (int ni = 0; ni < TILE_N; ++ni) {
        const int n = n0 + ni;

        float k[KPRED];   // wave-uniform address -> scalar (SGPR) loads
        {
            const float* kp = pred_kpts + (size_t)n * KPRED;
            #pragma unroll
            for (int i = 0; i < KPRED; ++i) k[i] = kp[i];
        }

        const float dx0 = k[0] - tx[0];
        const float dy0 = k[1] - ty[0];

        float cd = 0.0f;   // cost_deltas
        float ck = 0.0f;   // cost_kpts: xa - txa = 2*dx + dx0
        float cq = 0.0f;   // kpts-class squared distance
        #pragma unroll
        for (int j = 1; j < 18; ++j) {
            const float vj = (float)((vmask >> j) & 1u);
            const float dx = k[3 * j - 1] - tx[j];
            const float dy = k[3 * j]     - ty[j];
            cd = fmaf(vj, fabsf(dx) + fabsf(dy), cd);
            const float ax = fmaf(2.0f, dx, dx0);
            const float ay = fmaf(2.0f, dy, dy0);
            ck = fmaf(vj, fabsf(ax) + fabsf(ay), ck);
            const float d = k[3 * j + 1] - w[j];   // tid[j-1] == w[j]
            cq = fmaf(d, d, cq);
        }

        // cost_ctrs = vis0 * ||(dx0, dy0)||
        const float v0 = (float)(vmask & 1u);
        const float cc = v0 * sqrtf(fmaf(dx0, dx0, dy0 * dy0));

        // cost_class = -softmax(logits)[cls]
        const float l0 = lg[2 * ni], l1 = lg[2 * ni + 1];
        const float m  = fmaxf(l0, l1);
        const float e0 = __expf(l0 - m);
        const float e1 = __expf(l1 - m);
        const float inv = 1.0f / (e0 + e1);
        const float ccls = -((cls == 0) ? e0 : e1) * inv;

        out[(size_t)n * PN + p] = ck + cc + cd + ccls + sqrtf(cq);
    }
}

extern "C" void kernel_launch(void* const* d_in, const int* in_sizes, int n_in,
                              void* d_out, int out_size, void* d_ws, size_t ws_size,
                              hipStream_t stream) {
    const float* pred_logits = (const float*)d_in[0];
    const float* pred_kpts   = (const float*)d_in[1];
    const float* tgt_kpts    = (const float*)d_in[2];
    const int*   tgt_ids     = (const int*)d_in[3];
    float* out = (float*)d_out;

    dim3 grid(NN / TILE_N);   // 1200 blocks
    dim3 block(PN);           // 320 threads = 5 waves
    hipLaunchKernelGGL(hungarian_cost_kernel, grid, block, 0, stream,
                       pred_logits, pred_kpts, tgt_kpts, tgt_ids, out);
}